// Round 4
// baseline (528.595 us; speedup 1.0000x reference)
//
#include <hip/hip_runtime.h>
#include <hip/hip_bf16.h>
#include <math.h>

typedef __attribute__((ext_vector_type(8))) short bf16x8;
typedef __attribute__((ext_vector_type(4))) float f32x4;

#define N_TOK 1024
#define HID   2048
#define NEXP  16
#define NE2   18      // 16 routed + 2 shared pseudo-experts
#define INTER 1024
#define TOPK  6
#define CAP   1024

__device__ __forceinline__ unsigned short f2bf(float f) {
  unsigned u = __builtin_bit_cast(unsigned, f);
  u += 0x7fffu + ((u >> 16) & 1u);          // round-to-nearest-even
  return (unsigned short)(u >> 16);
}
__device__ __forceinline__ float b2f(short s) {
  unsigned u = ((unsigned)(unsigned short)s) << 16;
  return __builtin_bit_cast(float, u);
}
__device__ __forceinline__ void gll16(const void* g, void* l) {
  __builtin_amdgcn_global_load_lds(
      (const __attribute__((address_space(1))) unsigned int*)g,
      (__attribute__((address_space(3))) unsigned int*)l, 16, 0, 0);
}

// ---------------------------------------------------------------- router ----
__global__ __launch_bounds__(256) void router_k(
    const float* __restrict__ x, const float* __restrict__ gw,
    const float* __restrict__ gb, int* __restrict__ counts,
    int* __restrict__ tok_list, int* __restrict__ meta,
    float* __restrict__ pwt, unsigned short* __restrict__ x_bf)
{
  const int t   = blockIdx.x;
  const int tid = threadIdx.x;
  __shared__ float xrow[HID];
  __shared__ float logits[NEXP];

  for (int i = tid; i < HID; i += 256) {
    float v = x[(size_t)t * HID + i];
    xrow[i] = v;
    x_bf[(size_t)t * HID + i] = f2bf(v);
  }
  __syncthreads();

  const int w = tid >> 6, lane = tid & 63;
  for (int s = 0; s < 4; ++s) {
    int e = w * 4 + s;
    const float* g = gw + (size_t)e * HID;
    float p = 0.f;
    for (int i = lane; i < HID; i += 64) p += xrow[i] * g[i];
    for (int off = 32; off; off >>= 1) p += __shfl_down(p, off);
    if (lane == 0) logits[e] = p;
  }
  __syncthreads();

  if (tid == 0) {
    float sc[NEXP], scorr[NEXP];
    for (int e = 0; e < NEXP; ++e) {
      float s1 = 1.f / (1.f + expf(-logits[e]));
      sc[e] = s1; scorr[e] = s1 + gb[e];
    }
    float gs[4];
    for (int g = 0; g < 4; ++g) {
      float m1 = -1e30f, m2 = -1e30f;
      for (int j = 0; j < 4; ++j) {
        float v = scorr[g * 4 + j];
        if (v > m1) { m2 = m1; m1 = v; } else if (v > m2) m2 = v;
      }
      gs[g] = m1 + m2;
    }
    int g1 = 0;
    for (int g = 1; g < 4; ++g) if (gs[g] > gs[g1]) g1 = g;
    int g2 = -1;
    for (int g = 0; g < 4; ++g) { if (g == g1) continue; if (g2 < 0 || gs[g] > gs[g2]) g2 = g; }

    bool taken[NEXP];
    for (int e = 0; e < NEXP; ++e) taken[e] = false;
    int ids[TOPK]; float wv[TOPK]; float wsum = 0.f;
    for (int k = 0; k < TOPK; ++k) {
      int best = -1; float bv = -1e30f;
      for (int e = 0; e < NEXP; ++e) {
        int grp = e >> 2;
        if (grp != g1 && grp != g2) continue;
        if (taken[e]) continue;
        if (scorr[e] > bv) { bv = scorr[e]; best = e; }
      }
      taken[best] = true; ids[k] = best; wv[k] = sc[best]; wsum += sc[best];
    }
    float inv = 2.5f / wsum;
    for (int k = 0; k < TOPK; ++k) {
      int e = ids[k];
      int slot = atomicAdd(&counts[e], 1);
      tok_list[e * CAP + slot] = t;
      meta[t * TOPK + k] = (e << 16) | slot;
      pwt[t * TOPK + k] = wv[k] * inv;
    }
  }
}

// ----------------------------------------------- weight convert+transpose ---
// v2: per-thread 4x4 in-register micro-transpose; LDS writes ds_write_b64,
// reads ds_read_b128; 16-B XOR swizzle both sides (consistent involution).
__global__ __launch_bounds__(256) void t_gu_k(
    const float* __restrict__ wgu, const float* __restrict__ sgu,
    unsigned short* __restrict__ dst)
{
  const int z = blockIdx.z;
  const int n0 = blockIdx.x * 64, k0 = blockIdx.y * 64;
  const float* src; int ld; int cb;
  if (z < 16) { src = wgu + (size_t)z * HID * (2 * INTER); ld = 2 * INTER; cb = n0; }
  else { int j = z - 16; src = sgu; ld = 4096;
         cb = (n0 < 1024) ? j * 1024 + n0 : 1024 * j + 1024 + n0; }
  __shared__ __align__(16) unsigned short t2[64][72];   // 144 B row stride
  const int tid = threadIdx.x;
  const int kb = tid >> 4, nb = tid & 15;               // 4x4 block
  unsigned short h[4][4];
  #pragma unroll
  for (int j = 0; j < 4; ++j) {
    float4 f = *(const float4*)(src + (size_t)(k0 + kb * 4 + j) * ld + cb + nb * 4);
    h[j][0] = f2bf(f.x); h[j][1] = f2bf(f.y); h[j][2] = f2bf(f.z); h[j][3] = f2bf(f.w);
  }
  #pragma unroll
  for (int i = 0; i < 4; ++i) {
    int rr = nb * 4 + i;
    unsigned lo  = h[0][i] | ((unsigned)h[1][i] << 16);
    unsigned hi2 = h[2][i] | ((unsigned)h[3][i] << 16);
    unsigned long long v = (unsigned long long)lo | ((unsigned long long)hi2 << 32);
    *(unsigned long long*)((char*)t2 + rr * 144 + ((kb * 8) ^ ((rr & 7) << 4))) = v;
  }
  __syncthreads();
  unsigned short* d = dst + (size_t)z * HID * (2 * INTER);
  #pragma unroll
  for (int i = 0; i < 2; ++i) {
    int c = tid + 256 * i;                 // 512 chunks of 16 B
    int nl = c >> 3, s = c & 7;
    uint4 v = *(const uint4*)((const char*)t2 + nl * 144 + ((s * 16) ^ ((nl & 7) << 4)));
    *(uint4*)(d + (size_t)(n0 + nl) * HID + k0 + s * 8) = v;
  }
}

__global__ __launch_bounds__(256) void t_d_k(
    const float* __restrict__ wd, const float* __restrict__ sd,
    unsigned short* __restrict__ dst)
{
  const int z = blockIdx.z;
  const int n0 = blockIdx.x * 64, k0 = blockIdx.y * 64;
  const float* src = (z < 16) ? wd + (size_t)z * INTER * HID
                              : sd + (size_t)(z - 16) * INTER * HID;
  __shared__ __align__(16) unsigned short t2[64][72];
  const int tid = threadIdx.x;
  const int kb = tid >> 4, nb = tid & 15;
  unsigned short h[4][4];
  #pragma unroll
  for (int j = 0; j < 4; ++j) {
    float4 f = *(const float4*)(src + (size_t)(k0 + kb * 4 + j) * HID + n0 + nb * 4);
    h[j][0] = f2bf(f.x); h[j][1] = f2bf(f.y); h[j][2] = f2bf(f.z); h[j][3] = f2bf(f.w);
  }
  #pragma unroll
  for (int i = 0; i < 4; ++i) {
    int rr = nb * 4 + i;
    unsigned lo  = h[0][i] | ((unsigned)h[1][i] << 16);
    unsigned hi2 = h[2][i] | ((unsigned)h[3][i] << 16);
    unsigned long long v = (unsigned long long)lo | ((unsigned long long)hi2 << 32);
    *(unsigned long long*)((char*)t2 + rr * 144 + ((kb * 8) ^ ((rr & 7) << 4))) = v;
  }
  __syncthreads();
  unsigned short* d = dst + (size_t)z * HID * INTER;
  #pragma unroll
  for (int i = 0; i < 2; ++i) {
    int c = tid + 256 * i;
    int nl = c >> 3, s = c & 7;
    uint4 v = *(const uint4*)((const char*)t2 + nl * 144 + ((s * 16) ^ ((nl & 7) << 4)));
    *(uint4*)(d + (size_t)(n0 + nl) * INTER + k0 + s * 8) = v;
  }
}

// ------------------------------------------ 256x256 8-phase grouped GEMM ----
// 8 waves (2M x 4N), BK=64, double-buffered LDS (128 KiB). Per tile: 4 phases,
// each = {prefetch-issue | 4-12 ds_read_b128 | setprio(1) 16 MFMA setprio(0) |
// s_barrier}. Prefetch of tile t+1 issued in phases 1-2, drained by a single
// vmcnt(0) at end of phase 4 (~3 phases of MFMA cover the HBM latency).
// MODE 0: swiglu -> bf16 act (n0 covers 128 swiglu cols; B rows 0..127 = g,
// 128..255 = u at +1024). MODE 1: plain bf16 store (BN=256).
template<int MODE>
__global__ __launch_bounds__(512, 2) void gemm8_k(
    const unsigned short* __restrict__ A, int lda, size_t a_estride,
    const unsigned short* __restrict__ Wt, int K, size_t w_estride,
    const int* __restrict__ counts, const int* __restrict__ tok_list,
    unsigned short* __restrict__ outb, int out_ld, size_t out_estride)
{
  const int e  = blockIdx.z;
  const int m0 = blockIdx.y * 256;
  const int M  = (e < 16) ? counts[e] : N_TOK;
  if (m0 >= M) return;
  const int n0 = blockIdx.x * (MODE == 0 ? 128 : 256);

  __shared__ __align__(16) unsigned short lds[4][256 * 64]; // A0,B0,A1,B1

  const int tid = threadIdx.x, lane = tid & 63, wid = tid >> 6;
  const int wm = wid >> 2, wn = wid & 3, l15 = lane & 15, hi = lane >> 4;

  const unsigned short* Ap = A + (size_t)e * a_estride;
  const unsigned short* Wp = Wt + (size_t)e * w_estride;

  // staging descriptors: 4 A-chunks + 4 B-chunks of 16 B per thread per tile
  const unsigned short* asrc[4]; const unsigned short* bsrc[4];
  #pragma unroll
  for (int i = 0; i < 4; ++i) {
    int c = tid + 512 * i;                 // 0..2047
    int r = c >> 3, s = c & 7, sl = s ^ (r & 7);
    int slot = m0 + r;
    int row;
    if (MODE == 0) row = (e < 16) ? ((slot < M) ? tok_list[e * CAP + slot] : 0) : slot;
    else           row = slot;
    asrc[i] = Ap + (size_t)row * lda + sl * 8;
    int nrow = (MODE == 0) ? ((r < 128) ? n0 + r : 1024 + n0 + (r - 128)) : (n0 + r);
    bsrc[i] = Wp + (size_t)nrow * K + sl * 8;
  }

  int bn[4];
  if (MODE == 0) { bn[0] = wn*32; bn[1] = wn*32+16; bn[2] = 128+wn*32; bn[3] = 144+wn*32; }
  else           { bn[0] = wn*64; bn[1] = wn*64+16; bn[2] = wn*64+32; bn[3] = wn*64+48; }

  f32x4 acc[8][4];
  #pragma unroll
  for (int a0 = 0; a0 < 8; ++a0)
    #pragma unroll
    for (int b0 = 0; b0 < 4; ++b0) acc[a0][b0] = (f32x4){0.f, 0.f, 0.f, 0.f};

  bf16x8 af[8], bv[4];
  const int ksel = hi * 8;     // per-lane k base within 16-lane group

  // LDS fragment read helpers (T2 XOR swizzle, matches pre-swizzled source)
  auto rdA = [&](const char* Ab, int mh) {
    #pragma unroll
    for (int mi = 0; mi < 4; ++mi)
      #pragma unroll
      for (int ks = 0; ks < 2; ++ks) {
        int r = wm * 128 + mh * 64 + mi * 16 + l15;
        af[mi * 2 + ks] = *(const bf16x8*)(Ab + r * 128 + (((ks * 32 + ksel) * 2) ^ ((r & 7) << 4)));
      }
  };
  auto rdB = [&](const char* Bb, int nh) {
    #pragma unroll
    for (int ni = 0; ni < 2; ++ni)
      #pragma unroll
      for (int ks = 0; ks < 2; ++ks) {
        int r = bn[nh * 2 + ni] + l15;
        bv[ni * 2 + ks] = *(const bf16x8*)(Bb + r * 128 + (((ks * 32 + ksel) * 2) ^ ((r & 7) << 4)));
      }
  };
  auto quad = [&](int mh, int nh) {
    __builtin_amdgcn_s_setprio(1);
    #pragma unroll
    for (int mi = 0; mi < 4; ++mi)
      #pragma unroll
      for (int ni = 0; ni < 2; ++ni)
        #pragma unroll
        for (int ks = 0; ks < 2; ++ks)
          acc[mh * 4 + mi][nh * 2 + ni] =
            __builtin_amdgcn_mfma_f32_16x16x32_bf16(af[mi * 2 + ks], bv[ni * 2 + ks],
                                                    acc[mh * 4 + mi][nh * 2 + ni], 0, 0, 0);
    __builtin_amdgcn_s_setprio(0);
  };

  const int nt = K >> 6;
  // prologue: stage tile 0 into buffer 0
  #pragma unroll
  for (int i = 0; i < 4; ++i) {
    gll16(asrc[i], (char*)lds[0] + (tid + 512 * i) * 16);
    gll16(bsrc[i], (char*)lds[1] + (tid + 512 * i) * 16);
  }
  asm volatile("s_waitcnt vmcnt(0)" ::: "memory");
  __builtin_amdgcn_s_barrier();

  int p = 0;
  for (int t = 0; t < nt; ++t) {
    const char* Ab = (const char*)lds[p * 2];
    const char* Bb = (const char*)lds[p * 2 + 1];
    const int kt1 = (t + 1) << 6;
    const bool pf = (t + 1 < nt);

    // P1: issue A-prefetch; Q(mh0, nh0)
    if (pf) {
      #pragma unroll
      for (int i = 0; i < 4; ++i)
        gll16(asrc[i] + kt1, (char*)lds[(p ^ 1) * 2] + (tid + 512 * i) * 16);
    }
    rdA(Ab, 0); rdB(Bb, 0);
    quad(0, 0);
    __builtin_amdgcn_s_barrier();

    // P2: issue B-prefetch; Q(mh0, nh1)
    if (pf) {
      #pragma unroll
      for (int i = 0; i < 4; ++i)
        gll16(bsrc[i] + kt1, (char*)lds[(p ^ 1) * 2 + 1] + (tid + 512 * i) * 16);
    }
    rdB(Bb, 1);
    quad(0, 1);
    __builtin_amdgcn_s_barrier();

    // P3: Q(mh1, nh1)
    rdA(Ab, 1);
    quad(1, 1);
    __builtin_amdgcn_s_barrier();

    // P4: Q(mh1, nh0); drain prefetch; swap
    rdB(Bb, 0);
    quad(1, 0);
    asm volatile("s_waitcnt vmcnt(0)" ::: "memory");
    __builtin_amdgcn_s_barrier();
    p ^= 1;
  }

  // ---- epilogue ----  C/D: col=lane&15, row=(lane>>4)*4+reg
  const int rbase = hi * 4;
  if (MODE == 0) {
    #pragma unroll
    for (int mi = 0; mi < 8; ++mi)
      #pragma unroll
      for (int rr = 0; rr < 4; ++rr) {
        int slot = m0 + wm * 128 + mi * 16 + rbase + rr;
        if (slot >= M) continue;
        #pragma unroll
        for (int j = 0; j < 2; ++j) {
          float g = acc[mi][j][rr], u = acc[mi][j + 2][rr];
          float sv = g / (1.f + expf(-g)) * u;
          int col = n0 + wn * 32 + j * 16 + l15;
          outb[(size_t)e * out_estride + (size_t)slot * out_ld + col] = f2bf(sv);
        }
      }
  } else {
    #pragma unroll
    for (int mi = 0; mi < 8; ++mi)
      #pragma unroll
      for (int rr = 0; rr < 4; ++rr) {
        int slot = m0 + wm * 128 + mi * 16 + rbase + rr;
        if (slot >= M) continue;
        unsigned short* row = outb + (size_t)e * out_estride + (size_t)slot * out_ld;
        #pragma unroll
        for (int ni = 0; ni < 4; ++ni)
          row[n0 + bn[ni] + l15] = f2bf(acc[mi][ni][rr]);
      }
  }
}

// ---------------------------------------------------------------- combine ---
__global__ __launch_bounds__(256) void combine_k(
    const unsigned short* __restrict__ ybuf, const int* __restrict__ meta,
    const float* __restrict__ pwt, float* __restrict__ out)
{
  const int t = blockIdx.x;
  const int c0 = threadIdx.x * 8;
  float acc[8];
  {
    bf16x8 v0 = *(const bf16x8*)(ybuf + ((size_t)16 * CAP + t) * HID + c0);
    bf16x8 v1 = *(const bf16x8*)(ybuf + ((size_t)17 * CAP + t) * HID + c0);
    #pragma unroll
    for (int j = 0; j < 8; ++j) acc[j] = b2f(v0[j]) + b2f(v1[j]);
  }
  #pragma unroll
  for (int k = 0; k < TOPK; ++k) {
    int m = meta[t * TOPK + k];
    float w = pwt[t * TOPK + k];
    int e = m >> 16, s = m & 0xffff;
    bf16x8 v = *(const bf16x8*)(ybuf + ((size_t)e * CAP + s) * HID + c0);
    #pragma unroll
    for (int j = 0; j < 8; ++j) acc[j] += w * b2f(v[j]);
  }
  float4* o = (float4*)(out + (size_t)t * HID + c0);
  o[0] = make_float4(acc[0], acc[1], acc[2], acc[3]);
  o[1] = make_float4(acc[4], acc[5], acc[6], acc[7]);
}

// --------------------------------------------------------------- launcher ---
extern "C" void kernel_launch(void* const* d_in, const int* in_sizes, int n_in,
                              void* d_out, int out_size, void* d_ws, size_t ws_size,
                              hipStream_t stream) {
  const float* x   = (const float*)d_in[0];
  const float* gw  = (const float*)d_in[1];
  const float* gb  = (const float*)d_in[2];
  const float* wgu = (const float*)d_in[3];
  const float* wd  = (const float*)d_in[4];
  const float* sgu = (const float*)d_in[5];
  const float* sd  = (const float*)d_in[6];
  float* out = (float*)d_out;

  char* ws = (char*)d_ws;
  int*   counts   = (int*)ws;                              // 256 B
  int*   tok_list = (int*)(ws + 256);                      // 64 KB
  int*   meta     = (int*)(ws + 256 + 65536);              // 24 KB
  float* pwt      = (float*)(ws + 256 + 65536 + 24576);    // 24 KB
  unsigned short* x_bf  = (unsigned short*)(ws + 128 * 1024);          // 4 MiB
  unsigned short* act   = x_bf + (size_t)N_TOK * HID;                  // 36 MiB
  unsigned short* ybuf  = act + (size_t)NE2 * CAP * INTER;             // 72 MiB
  unsigned short* wt_gu = ybuf + (size_t)NE2 * CAP * HID;              // 144 MiB
  unsigned short* wt_d  = wt_gu + (size_t)NE2 * HID * 2 * INTER;       // 72 MiB
  const size_t need = (size_t)((char*)(wt_d + (size_t)NE2 * HID * INTER) - ws);
  if (ws_size < need) return;   // ws measured at 1 GiB; need ~328 MiB

  hipMemsetAsync(counts, 0, 256, stream);
  router_k<<<N_TOK, 256, 0, stream>>>(x, gw, gb, counts, tok_list, meta, pwt, x_bf);

  t_gu_k<<<dim3(2 * INTER / 64, HID / 64, NE2), 256, 0, stream>>>(wgu, sgu, wt_gu);
  t_d_k<<<dim3(HID / 64, INTER / 64, NE2), 256, 0, stream>>>(wd, sd, wt_d);

  // gemm1: [18] gather(x)[M,2048] @ wt_gu[e][n][k] -> swiglu -> act[e][M,1024]
  gemm8_k<0><<<dim3(INTER / 128, CAP / 256, NE2), 512, 0, stream>>>(
      x_bf, HID, 0, wt_gu, HID, (size_t)HID * 2 * INTER, counts, tok_list,
      act, INTER, (size_t)CAP * INTER);
  // gemm2: [18] act[e][M,1024] @ wt_d[e][n][k] -> ybuf[e][M,2048] (bf16)
  gemm8_k<1><<<dim3(HID / 256, CAP / 256, NE2), 512, 0, stream>>>(
      act, INTER, (size_t)CAP * INTER, wt_d, INTER, (size_t)HID * INTER, counts, nullptr,
      ybuf, HID, (size_t)CAP * HID);

  combine_k<<<N_TOK, 256, 0, stream>>>(ybuf, meta, pwt, out);
}

// Round 5
// 504.858 us; speedup vs baseline: 1.0470x; 1.0470x over previous
//
#include <hip/hip_runtime.h>
#include <hip/hip_bf16.h>
#include <math.h>

typedef __attribute__((ext_vector_type(8))) short bf16x8;
typedef __attribute__((ext_vector_type(4))) float f32x4;

#define N_TOK 1024
#define HID   2048
#define NEXP  16
#define NE2   18      // 16 routed + 2 shared pseudo-experts
#define INTER 1024
#define TOPK  6
#define CAP   1024

__device__ __forceinline__ unsigned short f2bf(float f) {
  unsigned u = __builtin_bit_cast(unsigned, f);
  u += 0x7fffu + ((u >> 16) & 1u);          // round-to-nearest-even
  return (unsigned short)(u >> 16);
}
__device__ __forceinline__ float b2f(short s) {
  unsigned u = ((unsigned)(unsigned short)s) << 16;
  return __builtin_bit_cast(float, u);
}
__device__ __forceinline__ void gll16(const void* g, void* l) {
  __builtin_amdgcn_global_load_lds(
      (const __attribute__((address_space(1))) unsigned int*)g,
      (__attribute__((address_space(3))) unsigned int*)l, 16, 0, 0);
}
// bijective XCD-contiguous work remap (m204)
__device__ __forceinline__ void xcd_remap(int& bx, int& by, int& bz) {
  int gx = gridDim.x, gy = gridDim.y;
  int nwg = gx * gy * (int)gridDim.z;
  int lid = bx + gx * (by + gy * bz);
  int q = nwg >> 3, r = nwg & 7;
  int xcd = lid & 7, i = lid >> 3;
  int swz = (xcd < r ? xcd * (q + 1) : r * (q + 1) + (xcd - r) * q) + i;
  bx = swz % gx; int t2 = swz / gx; by = t2 % gy; bz = t2 / gy;
}

// ---------------------------------------------------------------- router ----
__global__ __launch_bounds__(256) void router_k(
    const float* __restrict__ x, const float* __restrict__ gw,
    const float* __restrict__ gb, int* __restrict__ counts,
    int* __restrict__ tok_list, int* __restrict__ meta,
    float* __restrict__ pwt, unsigned short* __restrict__ x_bf)
{
  const int t   = blockIdx.x;
  const int tid = threadIdx.x;
  __shared__ float xrow[HID];
  __shared__ float logits[NEXP];

  for (int i = tid; i < HID; i += 256) {
    float v = x[(size_t)t * HID + i];
    xrow[i] = v;
    x_bf[(size_t)t * HID + i] = f2bf(v);
  }
  __syncthreads();

  const int w = tid >> 6, lane = tid & 63;
  for (int s = 0; s < 4; ++s) {
    int e = w * 4 + s;
    const float* g = gw + (size_t)e * HID;
    float p = 0.f;
    for (int i = lane; i < HID; i += 64) p += xrow[i] * g[i];
    for (int off = 32; off; off >>= 1) p += __shfl_down(p, off);
    if (lane == 0) logits[e] = p;
  }
  __syncthreads();

  if (tid == 0) {
    float sc[NEXP], scorr[NEXP];
    for (int e = 0; e < NEXP; ++e) {
      float s1 = 1.f / (1.f + expf(-logits[e]));
      sc[e] = s1; scorr[e] = s1 + gb[e];
    }
    float gs[4];
    for (int g = 0; g < 4; ++g) {
      float m1 = -1e30f, m2 = -1e30f;
      for (int j = 0; j < 4; ++j) {
        float v = scorr[g * 4 + j];
        if (v > m1) { m2 = m1; m1 = v; } else if (v > m2) m2 = v;
      }
      gs[g] = m1 + m2;
    }
    int g1 = 0;
    for (int g = 1; g < 4; ++g) if (gs[g] > gs[g1]) g1 = g;
    int g2 = -1;
    for (int g = 0; g < 4; ++g) { if (g == g1) continue; if (g2 < 0 || gs[g] > gs[g2]) g2 = g; }

    bool taken[NEXP];
    for (int e = 0; e < NEXP; ++e) taken[e] = false;
    int ids[TOPK]; float wv[TOPK]; float wsum = 0.f;
    for (int k = 0; k < TOPK; ++k) {
      int best = -1; float bv = -1e30f;
      for (int e = 0; e < NEXP; ++e) {
        int grp = e >> 2;
        if (grp != g1 && grp != g2) continue;
        if (taken[e]) continue;
        if (scorr[e] > bv) { bv = scorr[e]; best = e; }
      }
      taken[best] = true; ids[k] = best; wv[k] = sc[best]; wsum += sc[best];
    }
    float inv = 2.5f / wsum;
    for (int k = 0; k < TOPK; ++k) {
      int e = ids[k];
      int slot = atomicAdd(&counts[e], 1);
      tok_list[e * CAP + slot] = t;
      meta[t * TOPK + k] = (e << 16) | slot;
      pwt[t * TOPK + k] = wv[k] * inv;
    }
  }
}

// ----------------------- 128x128 grouped GEMM, f32 B converted in-staging ---
// m97 structure: 4 waves (2x2), BK=64, single-buffer LDS (32 KiB), ~3 blk/CU.
// A: bf16 [row][K] via global_load_lds w=16, linear dest + inverse-swizzled
//    source; reads swizzled with ((r&7)<<4).
// B: f32 [k][n] loaded as 8x float4/thread (coalesced), cvt_pk_bf16_f32,
//    ds_write_b128 into [n][k] with ((n>>2)&7) slot-XOR (write conflict-free,
//    reads ~4-way).
// MODE 0: gemm1 (gather A by tok_list for e<16; B rows 0..63 g / 64..127 u;
//         swiglu -> bf16 act). MODE 1: gemm2 (plain bf16 store, BN=128).
template<int MODE>
__global__ __launch_bounds__(256, 3) void gemm_fw_k(
    const unsigned short* __restrict__ A, int lda, size_t a_estride,
    const float* __restrict__ Wr, const float* __restrict__ Ws, int K,
    const int* __restrict__ counts, const int* __restrict__ tok_list,
    unsigned short* __restrict__ outb, int out_ld, size_t out_estride)
{
  int bx = blockIdx.x, by = blockIdx.y, bz = blockIdx.z;
  xcd_remap(bx, by, bz);
  const int e  = bz;
  const int m0 = by * 128;
  const int M  = (e < 16) ? counts[e] : N_TOK;
  if (m0 >= M) return;
  const int n0 = bx * (MODE == 0 ? 64 : 128);

  __shared__ __align__(16) unsigned short Al[128 * 64];   // 16 KB
  __shared__ __align__(16) unsigned short Bl[128 * 64];   // 16 KB

  const int tid = threadIdx.x, lane = tid & 63, wid = tid >> 6;
  const int wm = wid >> 1, wn = wid & 1, l15 = lane & 15, hi = lane >> 4;

  const unsigned short* Ap = A + (size_t)e * a_estride;

  // ---- A staging descriptors (gll16, proven since R2) ----
  const unsigned short* asrc[4]; void* adst[4];
  #pragma unroll
  for (int i = 0; i < 4; ++i) {
    int c = tid + 256 * i;                 // 0..1023, 16B each
    int r = c >> 3, s = c & 7, sl = s ^ (r & 7);
    int slot = m0 + r;
    int row;
    if (MODE == 0) row = (e < 16) ? ((slot < M) ? tok_list[e * CAP + slot] : 0) : slot;
    else           row = slot;
    asrc[i] = Ap + (size_t)row * lda + sl * 8;
    adst[i] = (char*)Al + c * 16;
  }

  // ---- B staging setup: thread owns 4 n-rows (nq*4..+3) x 8 k (kb..kb+7) ----
  const int nq = tid & 31, kb8 = tid >> 5;   // k-base = kb8*8
  const float* bp; int ldw;
  {
    int n_ = nq * 4;
    if (MODE == 0) {
      if (e < 16) {
        size_t col = (n_ < 64) ? (size_t)(n0 + n_) : (size_t)(1024 + n0 + n_ - 64);
        bp = Wr + (size_t)e * HID * (2 * INTER) + col; ldw = 2 * INTER;
      } else {
        int j = e - 16;
        size_t col = (n_ < 64) ? (size_t)(j * 1024 + n0 + n_)
                               : (size_t)(2048 + j * 1024 + n0 + n_ - 64);
        bp = Ws + col; ldw = 4096;
      }
    } else {
      bp = ((e < 16) ? Wr + (size_t)e * INTER * HID
                     : Ws + (size_t)(e - 16) * INTER * HID) + (n0 + n_);
      ldw = HID;
    }
    bp += (size_t)(kb8 * 8) * ldw;
  }
  int bwoff[4];
  {
    int sp = (kb8 ^ (nq & 7)) << 4;
    #pragma unroll
    for (int j = 0; j < 4; ++j) bwoff[j] = (nq * 4 + j) * 128 + sp;
  }

  int bn[4];
  if (MODE == 0) { bn[0] = wn*32; bn[1] = wn*32+16; bn[2] = 64+wn*32; bn[3] = 80+wn*32; }
  else           { bn[0] = wn*64; bn[1] = wn*64+16; bn[2] = wn*64+32; bn[3] = wn*64+48; }

  f32x4 acc[4][4];
  #pragma unroll
  for (int a0 = 0; a0 < 4; ++a0)
    #pragma unroll
    for (int b0 = 0; b0 < 4; ++b0) acc[a0][b0] = (f32x4){0.f, 0.f, 0.f, 0.f};

  for (int kt = 0; kt < K; kt += 64) {
    // B: 8 coalesced f32x4 loads (k = kt+kb8*8+i, n = nq*4..+3)
    float4 bf4[8];
    #pragma unroll
    for (int i = 0; i < 8; ++i)
      bf4[i] = *(const float4*)(bp + (size_t)(kt + i) * ldw);
    // A: async direct-to-LDS
    #pragma unroll
    for (int i = 0; i < 4; ++i) gll16(asrc[i] + kt, adst[i]);
    // B: convert + transpose-in-regs + vector LDS write
    #pragma unroll
    for (int j = 0; j < 4; ++j) {
      unsigned w4[4];
      #pragma unroll
      for (int p = 0; p < 4; ++p) {
        float lo  = ((const float*)(bf4 + 2 * p))[j];
        float hi2 = ((const float*)(bf4 + 2 * p + 1))[j];
        unsigned rr;
        asm("v_cvt_pk_bf16_f32 %0, %1, %2" : "=v"(rr) : "v"(lo), "v"(hi2));
        w4[p] = rr;
      }
      *(uint4*)((char*)Bl + bwoff[j]) = *(uint4*)w4;
    }
    __syncthreads();

    #pragma unroll
    for (int kk = 0; kk < 64; kk += 32) {
      bf16x8 af[4], bv[4];
      #pragma unroll
      for (int mi = 0; mi < 4; ++mi) {
        int r = wm * 64 + mi * 16 + l15;
        int off = (r * 128 + (kk + hi * 8) * 2) ^ ((r & 7) << 4);
        af[mi] = *(const bf16x8*)((const char*)Al + off);
      }
      #pragma unroll
      for (int ni = 0; ni < 4; ++ni) {
        int r = bn[ni] + l15;
        int off = r * 128 + (((((kk >> 3) + hi)) ^ ((r >> 2) & 7)) << 4);
        bv[ni] = *(const bf16x8*)((const char*)Bl + off);
      }
      #pragma unroll
      for (int mi = 0; mi < 4; ++mi)
        #pragma unroll
        for (int ni = 0; ni < 4; ++ni)
          acc[mi][ni] = __builtin_amdgcn_mfma_f32_16x16x32_bf16(af[mi], bv[ni], acc[mi][ni], 0, 0, 0);
    }
    __syncthreads();
  }

  // ---- epilogue ----  C/D: col=lane&15, row=(lane>>4)*4+reg
  const int rbase = hi * 4;
  if (MODE == 0) {
    #pragma unroll
    for (int mi = 0; mi < 4; ++mi)
      #pragma unroll
      for (int rr = 0; rr < 4; ++rr) {
        int slot = m0 + wm * 64 + mi * 16 + rbase + rr;
        if (slot >= M) continue;
        #pragma unroll
        for (int j = 0; j < 2; ++j) {
          float g = acc[mi][j][rr], u = acc[mi][j + 2][rr];
          float sv = g / (1.f + expf(-g)) * u;
          int col = n0 + wn * 32 + j * 16 + l15;
          outb[(size_t)e * out_estride + (size_t)slot * out_ld + col] = f2bf(sv);
        }
      }
  } else {
    #pragma unroll
    for (int mi = 0; mi < 4; ++mi)
      #pragma unroll
      for (int rr = 0; rr < 4; ++rr) {
        int slot = m0 + wm * 64 + mi * 16 + rbase + rr;
        if (slot >= M) continue;
        unsigned short* row = outb + (size_t)e * out_estride + (size_t)slot * out_ld;
        #pragma unroll
        for (int ni = 0; ni < 4; ++ni)
          row[n0 + bn[ni] + l15] = f2bf(acc[mi][ni][rr]);
      }
  }
}

// ---------------------------------------------------------------- combine ---
__global__ __launch_bounds__(256) void combine_k(
    const unsigned short* __restrict__ ybuf, const int* __restrict__ meta,
    const float* __restrict__ pwt, float* __restrict__ out)
{
  const int t = blockIdx.x;
  const int c0 = threadIdx.x * 8;
  float acc[8];
  {
    bf16x8 v0 = *(const bf16x8*)(ybuf + ((size_t)16 * CAP + t) * HID + c0);
    bf16x8 v1 = *(const bf16x8*)(ybuf + ((size_t)17 * CAP + t) * HID + c0);
    #pragma unroll
    for (int j = 0; j < 8; ++j) acc[j] = b2f(v0[j]) + b2f(v1[j]);
  }
  #pragma unroll
  for (int k = 0; k < TOPK; ++k) {
    int m = meta[t * TOPK + k];
    float w = pwt[t * TOPK + k];
    int e = m >> 16, s = m & 0xffff;
    bf16x8 v = *(const bf16x8*)(ybuf + ((size_t)e * CAP + s) * HID + c0);
    #pragma unroll
    for (int j = 0; j < 8; ++j) acc[j] += w * b2f(v[j]);
  }
  float4* o = (float4*)(out + (size_t)t * HID + c0);
  o[0] = make_float4(acc[0], acc[1], acc[2], acc[3]);
  o[1] = make_float4(acc[4], acc[5], acc[6], acc[7]);
}

// --------------------------------------------------------------- launcher ---
extern "C" void kernel_launch(void* const* d_in, const int* in_sizes, int n_in,
                              void* d_out, int out_size, void* d_ws, size_t ws_size,
                              hipStream_t stream) {
  const float* x   = (const float*)d_in[0];
  const float* gw  = (const float*)d_in[1];
  const float* gb  = (const float*)d_in[2];
  const float* wgu = (const float*)d_in[3];
  const float* wd  = (const float*)d_in[4];
  const float* sgu = (const float*)d_in[5];
  const float* sd  = (const float*)d_in[6];
  float* out = (float*)d_out;

  char* ws = (char*)d_ws;
  int*   counts   = (int*)ws;                              // 256 B
  int*   tok_list = (int*)(ws + 256);                      // 64 KB
  int*   meta     = (int*)(ws + 256 + 65536);              // 24 KB
  float* pwt      = (float*)(ws + 256 + 65536 + 24576);    // 24 KB
  unsigned short* x_bf = (unsigned short*)(ws + 128 * 1024);          // 4 MiB
  unsigned short* act  = x_bf + (size_t)N_TOK * HID;                  // 36 MiB
  unsigned short* ybuf = act + (size_t)NE2 * CAP * INTER;             // 72 MiB
  const size_t need = (size_t)((char*)(ybuf + (size_t)NE2 * CAP * HID) - ws);
  if (ws_size < need) return;   // ws measured at 1 GiB; need ~112 MiB

  hipMemsetAsync(counts, 0, 256, stream);
  router_k<<<N_TOK, 256, 0, stream>>>(x, gw, gb, counts, tok_list, meta, pwt, x_bf);

  // gemm1: [18] gather(x)[M,2048] @ (wgu|sgu f32, converted in-staging)
  //        -> swiglu -> act[e][M,1024]
  gemm_fw_k<0><<<dim3(INTER / 64, CAP / 128, NE2), 256, 0, stream>>>(
      x_bf, HID, 0, wgu, sgu, HID, counts, tok_list,
      act, INTER, (size_t)CAP * INTER);
  // gemm2: [18] act[e][M,1024] @ (wd|sd f32, converted in-staging)
  //        -> ybuf[e][M,2048] (bf16)
  gemm_fw_k<1><<<dim3(HID / 128, CAP / 128, NE2), 256, 0, stream>>>(
      act, INTER, (size_t)CAP * INTER, wd, sd, INTER, counts, nullptr,
      ybuf, HID, (size_t)CAP * HID);

  combine_k<<<N_TOK, 256, 0, stream>>>(ybuf, meta, pwt, out);
}

// Round 6
// 478.992 us; speedup vs baseline: 1.1036x; 1.0540x over previous
//
#include <hip/hip_runtime.h>
#include <hip/hip_bf16.h>
#include <math.h>

typedef __attribute__((ext_vector_type(8))) short bf16x8;
typedef __attribute__((ext_vector_type(4))) float f32x4;

#define N_TOK 1024
#define HID   2048
#define NEXP  16
#define NE2   18      // 16 routed + 2 shared pseudo-experts
#define INTER 1024
#define TOPK  6
#define CAP   1024

__device__ __forceinline__ unsigned short f2bf(float f) {
  unsigned u = __builtin_bit_cast(unsigned, f);
  u += 0x7fffu + ((u >> 16) & 1u);          // round-to-nearest-even
  return (unsigned short)(u >> 16);
}
__device__ __forceinline__ float b2f(short s) {
  unsigned u = ((unsigned)(unsigned short)s) << 16;
  return __builtin_bit_cast(float, u);
}
__device__ __forceinline__ void gll16(const void* g, void* l) {
  __builtin_amdgcn_global_load_lds(
      (const __attribute__((address_space(1))) unsigned int*)g,
      (__attribute__((address_space(3))) unsigned int*)l, 16, 0, 0);
}
// bijective XCD-contiguous work remap (m204)
__device__ __forceinline__ void xcd_remap(int& bx, int& by, int& bz) {
  int gx = gridDim.x, gy = gridDim.y;
  int nwg = gx * gy * (int)gridDim.z;
  int lid = bx + gx * (by + gy * bz);
  int q = nwg >> 3, r = nwg & 7;
  int xcd = lid & 7, i = lid >> 3;
  int swz = (xcd < r ? xcd * (q + 1) : r * (q + 1) + (xcd - r) * q) + i;
  bx = swz % gx; int t2 = swz / gx; by = t2 % gy; bz = t2 / gy;
}

// ---------------------------------------------------------------- router ----
__global__ __launch_bounds__(256) void router_k(
    const float* __restrict__ x, const float* __restrict__ gw,
    const float* __restrict__ gb, int* __restrict__ counts,
    int* __restrict__ tok_list, int* __restrict__ meta,
    float* __restrict__ pwt, unsigned short* __restrict__ x_bf)
{
  const int t   = blockIdx.x;
  const int tid = threadIdx.x;
  __shared__ float xrow[HID];
  __shared__ float logits[NEXP];

  for (int i = tid; i < HID; i += 256) {
    float v = x[(size_t)t * HID + i];
    xrow[i] = v;
    x_bf[(size_t)t * HID + i] = f2bf(v);
  }
  __syncthreads();

  const int w = tid >> 6, lane = tid & 63;
  for (int s = 0; s < 4; ++s) {
    int e = w * 4 + s;
    const float* g = gw + (size_t)e * HID;
    float p = 0.f;
    for (int i = lane; i < HID; i += 64) p += xrow[i] * g[i];
    for (int off = 32; off; off >>= 1) p += __shfl_down(p, off);
    if (lane == 0) logits[e] = p;
  }
  __syncthreads();

  if (tid == 0) {
    float sc[NEXP], scorr[NEXP];
    for (int e = 0; e < NEXP; ++e) {
      float s1 = 1.f / (1.f + expf(-logits[e]));
      sc[e] = s1; scorr[e] = s1 + gb[e];
    }
    float gs[4];
    for (int g = 0; g < 4; ++g) {
      float m1 = -1e30f, m2 = -1e30f;
      for (int j = 0; j < 4; ++j) {
        float v = scorr[g * 4 + j];
        if (v > m1) { m2 = m1; m1 = v; } else if (v > m2) m2 = v;
      }
      gs[g] = m1 + m2;
    }
    int g1 = 0;
    for (int g = 1; g < 4; ++g) if (gs[g] > gs[g1]) g1 = g;
    int g2 = -1;
    for (int g = 0; g < 4; ++g) { if (g == g1) continue; if (g2 < 0 || gs[g] > gs[g2]) g2 = g; }

    bool taken[NEXP];
    for (int e = 0; e < NEXP; ++e) taken[e] = false;
    int ids[TOPK]; float wv[TOPK]; float wsum = 0.f;
    for (int k = 0; k < TOPK; ++k) {
      int best = -1; float bv = -1e30f;
      for (int e = 0; e < NEXP; ++e) {
        int grp = e >> 2;
        if (grp != g1 && grp != g2) continue;
        if (taken[e]) continue;
        if (scorr[e] > bv) { bv = scorr[e]; best = e; }
      }
      taken[best] = true; ids[k] = best; wv[k] = sc[best]; wsum += sc[best];
    }
    float inv = 2.5f / wsum;
    for (int k = 0; k < TOPK; ++k) {
      int e = ids[k];
      int slot = atomicAdd(&counts[e], 1);
      tok_list[e * CAP + slot] = t;
      meta[t * TOPK + k] = (e << 16) | slot;
      pwt[t * TOPK + k] = wv[k] * inv;
    }
  }
}

// ------------- 128x128 grouped GEMM, f32 B converted in-staging, T14 dbuf ---
// 4 waves (2x2), BK=64, DOUBLE-buffered LDS (64 KiB -> 2 blk/CU).
// Per K-tile: issue ALL of tile t+1's traffic (4 gll-A direct-to-LDS + 8
// coalesced f32x4 B-loads to regs) BEFORE compute of tile t; after compute,
// vmcnt(0) (loads arrived under ~600cyc of MFMA cover) + cvt_pk + 4
// ds_write_b128 into the other buffer; ONE barrier per tile.
// B swizzle: slot ^ ((r>>2)&7) ^ ((r&3)<<1): write conflict-free, read 2-way.
// MODE 0: gemm1 (gather A rows; B rows 0..63 g / 64..127 u; swiglu->bf16).
// MODE 1: gemm2 (plain bf16 store, BN=128).
template<int MODE>
__global__ __launch_bounds__(256, 2) void gemm_fw_k(
    const unsigned short* __restrict__ A, int lda, size_t a_estride,
    const float* __restrict__ Wr, const float* __restrict__ Ws, int K,
    const int* __restrict__ counts, const int* __restrict__ tok_list,
    unsigned short* __restrict__ outb, int out_ld, size_t out_estride)
{
  int bx = blockIdx.x, by = blockIdx.y, bz = blockIdx.z;
  xcd_remap(bx, by, bz);
  const int e  = bz;
  const int m0 = by * 128;
  const int M  = (e < 16) ? counts[e] : N_TOK;
  if (m0 >= M) return;
  const int n0 = bx * (MODE == 0 ? 64 : 128);

  __shared__ __align__(16) unsigned short Al[2][128 * 64];   // 2 x 16 KB
  __shared__ __align__(16) unsigned short Bl[2][128 * 64];   // 2 x 16 KB

  const int tid = threadIdx.x, lane = tid & 63, wid = tid >> 6;
  const int wm = wid >> 1, wn = wid & 1, l15 = lane & 15, hi = lane >> 4;

  const unsigned short* Ap = A + (size_t)e * a_estride;

  // ---- A staging descriptors (gll16 w=16, inverse-swizzled source) ----
  const unsigned short* asrc[4]; int aoff[4];
  #pragma unroll
  for (int i = 0; i < 4; ++i) {
    int c = tid + 256 * i;                 // 0..1023, 16B each
    int r = c >> 3, s = c & 7, sl = s ^ (r & 7);
    int slot = m0 + r;
    int row;
    if (MODE == 0) row = (e < 16) ? ((slot < M) ? tok_list[e * CAP + slot] : 0) : slot;
    else           row = slot;
    asrc[i] = Ap + (size_t)row * lda + sl * 8;
    aoff[i] = c * 16;
  }

  // ---- B staging: thread owns n-rows nq*4..+3, k-range kb8*8..+7 ----
  const int nq = tid & 31, kb8 = tid >> 5;
  const float* bp; int ldw;
  {
    int n_ = nq * 4;
    if (MODE == 0) {
      if (e < 16) {
        size_t col = (n_ < 64) ? (size_t)(n0 + n_) : (size_t)(1024 + n0 + n_ - 64);
        bp = Wr + (size_t)e * HID * (2 * INTER) + col; ldw = 2 * INTER;
      } else {
        int j = e - 16;
        size_t col = (n_ < 64) ? (size_t)(j * 1024 + n0 + n_)
                               : (size_t)(2048 + j * 1024 + n0 + n_ - 64);
        bp = Ws + col; ldw = 4096;
      }
    } else {
      bp = ((e < 16) ? Wr + (size_t)e * INTER * HID
                     : Ws + (size_t)(e - 16) * INTER * HID) + (n0 + n_);
      ldw = HID;
    }
    bp += (size_t)(kb8 * 8) * ldw;
  }
  int bwoff[4];
  #pragma unroll
  for (int j = 0; j < 4; ++j)
    bwoff[j] = (nq * 4 + j) * 128 + ((kb8 ^ (nq & 7) ^ (j << 1)) << 4);

  int bn[4];
  if (MODE == 0) { bn[0] = wn*32; bn[1] = wn*32+16; bn[2] = 64+wn*32; bn[3] = 80+wn*32; }
  else           { bn[0] = wn*64; bn[1] = wn*64+16; bn[2] = wn*64+32; bn[3] = wn*64+48; }

  f32x4 acc[4][4];
  #pragma unroll
  for (int a0 = 0; a0 < 4; ++a0)
    #pragma unroll
    for (int b0 = 0; b0 < 4; ++b0) acc[a0][b0] = (f32x4){0.f, 0.f, 0.f, 0.f};

  float4 bf4[8];
  #define LOADB(kt)                                                         \
    _Pragma("unroll")                                                       \
    for (int i = 0; i < 8; ++i)                                             \
      bf4[i] = *(const float4*)(bp + (size_t)((kt) + i) * ldw);
  #define WRITEB(Bb)                                                        \
    _Pragma("unroll")                                                       \
    for (int j = 0; j < 4; ++j) {                                           \
      unsigned w4[4];                                                       \
      _Pragma("unroll")                                                     \
      for (int q2 = 0; q2 < 4; ++q2) {                                      \
        float lo  = ((const float*)(bf4 + 2 * q2))[j];                      \
        float hi2 = ((const float*)(bf4 + 2 * q2 + 1))[j];                  \
        unsigned rr;                                                        \
        asm("v_cvt_pk_bf16_f32 %0, %1, %2" : "=v"(rr) : "v"(lo), "v"(hi2)); \
        w4[q2] = rr;                                                        \
      }                                                                     \
      *(uint4*)((char*)(Bb) + bwoff[j]) = *(uint4*)w4;                      \
    }

  // ---- prologue: stage tile 0 into buffer 0 ----
  LOADB(0)
  #pragma unroll
  for (int i = 0; i < 4; ++i) gll16(asrc[i], (char*)Al[0] + aoff[i]);
  asm volatile("s_waitcnt vmcnt(0)" ::: "memory");
  WRITEB(Bl[0])
  __syncthreads();

  const int nt = K >> 6;
  int p = 0;
  for (int t = 0; t < nt; ++t) {
    const bool pf = (t + 1 < nt);
    if (pf) {
      const int kt1 = (t + 1) << 6;
      #pragma unroll
      for (int i = 0; i < 4; ++i)
        gll16(asrc[i] + kt1, (char*)Al[p ^ 1] + aoff[i]);
      LOADB(kt1)
    }

    const char* Ab = (const char*)Al[p];
    const char* Bb = (const char*)Bl[p];
    #pragma unroll
    for (int kk = 0; kk < 64; kk += 32) {
      bf16x8 af[4], bv[4];
      #pragma unroll
      for (int mi = 0; mi < 4; ++mi) {
        int r = wm * 64 + mi * 16 + l15;
        int off = (r * 128 + (kk + hi * 8) * 2) ^ ((r & 7) << 4);
        af[mi] = *(const bf16x8*)(Ab + off);
      }
      #pragma unroll
      for (int ni = 0; ni < 4; ++ni) {
        int r = bn[ni] + l15;
        int slot = (kk >> 3) + hi;
        int off = r * 128 + ((slot ^ ((r >> 2) & 7) ^ ((r & 3) << 1)) << 4);
        bv[ni] = *(const bf16x8*)(Bb + off);
      }
      #pragma unroll
      for (int mi = 0; mi < 4; ++mi)
        #pragma unroll
        for (int ni = 0; ni < 4; ++ni)
          acc[mi][ni] = __builtin_amdgcn_mfma_f32_16x16x32_bf16(af[mi], bv[ni], acc[mi][ni], 0, 0, 0);
    }

    if (pf) {
      asm volatile("s_waitcnt vmcnt(0)" ::: "memory");   // A glls + B regs landed
      WRITEB(Bl[p ^ 1])
    }
    __syncthreads();
    p ^= 1;
  }
  #undef LOADB
  #undef WRITEB

  // ---- epilogue ----  C/D: col=lane&15, row=(lane>>4)*4+reg
  const int rbase = hi * 4;
  if (MODE == 0) {
    #pragma unroll
    for (int mi = 0; mi < 4; ++mi)
      #pragma unroll
      for (int rr = 0; rr < 4; ++rr) {
        int slot = m0 + wm * 64 + mi * 16 + rbase + rr;
        if (slot >= M) continue;
        #pragma unroll
        for (int j = 0; j < 2; ++j) {
          float g = acc[mi][j][rr], u = acc[mi][j + 2][rr];
          float sv = g / (1.f + expf(-g)) * u;
          int col = n0 + wn * 32 + j * 16 + l15;
          outb[(size_t)e * out_estride + (size_t)slot * out_ld + col] = f2bf(sv);
        }
      }
  } else {
    #pragma unroll
    for (int mi = 0; mi < 4; ++mi)
      #pragma unroll
      for (int rr = 0; rr < 4; ++rr) {
        int slot = m0 + wm * 64 + mi * 16 + rbase + rr;
        if (slot >= M) continue;
        unsigned short* row = outb + (size_t)e * out_estride + (size_t)slot * out_ld;
        #pragma unroll
        for (int ni = 0; ni < 4; ++ni)
          row[n0 + bn[ni] + l15] = f2bf(acc[mi][ni][rr]);
      }
  }
}

// ---------------------------------------------------------------- combine ---
__global__ __launch_bounds__(256) void combine_k(
    const unsigned short* __restrict__ ybuf, const int* __restrict__ meta,
    const float* __restrict__ pwt, float* __restrict__ out)
{
  const int t = blockIdx.x;
  const int c0 = threadIdx.x * 8;
  float acc[8];
  {
    bf16x8 v0 = *(const bf16x8*)(ybuf + ((size_t)16 * CAP + t) * HID + c0);
    bf16x8 v1 = *(const bf16x8*)(ybuf + ((size_t)17 * CAP + t) * HID + c0);
    #pragma unroll
    for (int j = 0; j < 8; ++j) acc[j] = b2f(v0[j]) + b2f(v1[j]);
  }
  #pragma unroll
  for (int k = 0; k < TOPK; ++k) {
    int m = meta[t * TOPK + k];
    float w = pwt[t * TOPK + k];
    int e = m >> 16, s = m & 0xffff;
    bf16x8 v = *(const bf16x8*)(ybuf + ((size_t)e * CAP + s) * HID + c0);
    #pragma unroll
    for (int j = 0; j < 8; ++j) acc[j] += w * b2f(v[j]);
  }
  float4* o = (float4*)(out + (size_t)t * HID + c0);
  o[0] = make_float4(acc[0], acc[1], acc[2], acc[3]);
  o[1] = make_float4(acc[4], acc[5], acc[6], acc[7]);
}

// --------------------------------------------------------------- launcher ---
extern "C" void kernel_launch(void* const* d_in, const int* in_sizes, int n_in,
                              void* d_out, int out_size, void* d_ws, size_t ws_size,
                              hipStream_t stream) {
  const float* x   = (const float*)d_in[0];
  const float* gw  = (const float*)d_in[1];
  const float* gb  = (const float*)d_in[2];
  const float* wgu = (const float*)d_in[3];
  const float* wd  = (const float*)d_in[4];
  const float* sgu = (const float*)d_in[5];
  const float* sd  = (const float*)d_in[6];
  float* out = (float*)d_out;

  char* ws = (char*)d_ws;
  int*   counts   = (int*)ws;                              // 256 B
  int*   tok_list = (int*)(ws + 256);                      // 64 KB
  int*   meta     = (int*)(ws + 256 + 65536);              // 24 KB
  float* pwt      = (float*)(ws + 256 + 65536 + 24576);    // 24 KB
  unsigned short* x_bf = (unsigned short*)(ws + 128 * 1024);          // 4 MiB
  unsigned short* act  = x_bf + (size_t)N_TOK * HID;                  // 36 MiB
  unsigned short* ybuf = act + (size_t)NE2 * CAP * INTER;             // 72 MiB
  const size_t need = (size_t)((char*)(ybuf + (size_t)NE2 * CAP * HID) - ws);
  if (ws_size < need) return;   // ws measured at 1 GiB; need ~112 MiB

  hipMemsetAsync(counts, 0, 256, stream);
  router_k<<<N_TOK, 256, 0, stream>>>(x, gw, gb, counts, tok_list, meta, pwt, x_bf);

  // gemm1: [18] gather(x)[M,2048] @ (wgu|sgu f32, converted in-staging)
  //        -> swiglu -> act[e][M,1024]
  gemm_fw_k<0><<<dim3(INTER / 64, CAP / 128, NE2), 256, 0, stream>>>(
      x_bf, HID, 0, wgu, sgu, HID, counts, tok_list,
      act, INTER, (size_t)CAP * INTER);
  // gemm2: [18] act[e][M,1024] @ (wd|sd f32, converted in-staging)
  //        -> ybuf[e][M,2048] (bf16)
  gemm_fw_k<1><<<dim3(HID / 128, CAP / 128, NE2), 256, 0, stream>>>(
      act, INTER, (size_t)CAP * INTER, wd, sd, INTER, counts, nullptr,
      ybuf, HID, (size_t)CAP * HID);

  combine_k<<<N_TOK, 256, 0, stream>>>(ybuf, meta, pwt, out);
}

// Round 7
// 467.990 us; speedup vs baseline: 1.1295x; 1.0235x over previous
//
#include <hip/hip_runtime.h>
#include <hip/hip_bf16.h>
#include <math.h>

typedef __attribute__((ext_vector_type(8))) short bf16x8;
typedef __attribute__((ext_vector_type(4))) float f32x4;

#define N_TOK 1024
#define HID   2048
#define NEXP  16
#define NE2   18      // 16 routed + 2 shared pseudo-experts
#define INTER 1024
#define TOPK  6
#define CAP   1024

__device__ __forceinline__ unsigned short f2bf(float f) {
  unsigned u = __builtin_bit_cast(unsigned, f);
  u += 0x7fffu + ((u >> 16) & 1u);          // round-to-nearest-even
  return (unsigned short)(u >> 16);
}
__device__ __forceinline__ float b2f(short s) {
  unsigned u = ((unsigned)(unsigned short)s) << 16;
  return __builtin_bit_cast(float, u);
}
__device__ __forceinline__ void gll16(const void* g, void* l) {
  __builtin_amdgcn_global_load_lds(
      (const __attribute__((address_space(1))) unsigned int*)g,
      (__attribute__((address_space(3))) unsigned int*)l, 16, 0, 0);
}
// bijective XCD-contiguous work remap (m204)
__device__ __forceinline__ void xcd_remap(int& bx, int& by, int& bz) {
  int gx = gridDim.x, gy = gridDim.y;
  int nwg = gx * gy * (int)gridDim.z;
  int lid = bx + gx * (by + gy * bz);
  int q = nwg >> 3, r = nwg & 7;
  int xcd = lid & 7, i = lid >> 3;
  int swz = (xcd < r ? xcd * (q + 1) : r * (q + 1) + (xcd - r) * q) + i;
  bx = swz % gx; int t2 = swz / gx; by = t2 % gy; bz = t2 / gy;
}

// ---------------------------------------------------------------- router ----
__global__ __launch_bounds__(256) void router_k(
    const float* __restrict__ x, const float* __restrict__ gw,
    const float* __restrict__ gb, int* __restrict__ counts,
    int* __restrict__ tok_list, int* __restrict__ meta,
    float* __restrict__ pwt, unsigned short* __restrict__ x_bf)
{
  const int t   = blockIdx.x;
  const int tid = threadIdx.x;
  __shared__ float xrow[HID];
  __shared__ float logits[NEXP];

  for (int i = tid; i < HID; i += 256) {
    float v = x[(size_t)t * HID + i];
    xrow[i] = v;
    x_bf[(size_t)t * HID + i] = f2bf(v);
  }
  __syncthreads();

  const int w = tid >> 6, lane = tid & 63;
  for (int s = 0; s < 4; ++s) {
    int e = w * 4 + s;
    const float* g = gw + (size_t)e * HID;
    float p = 0.f;
    for (int i = lane; i < HID; i += 64) p += xrow[i] * g[i];
    for (int off = 32; off; off >>= 1) p += __shfl_down(p, off);
    if (lane == 0) logits[e] = p;
  }
  __syncthreads();

  if (tid == 0) {
    float sc[NEXP], scorr[NEXP];
    for (int e = 0; e < NEXP; ++e) {
      float s1 = 1.f / (1.f + expf(-logits[e]));
      sc[e] = s1; scorr[e] = s1 + gb[e];
    }
    float gs[4];
    for (int g = 0; g < 4; ++g) {
      float m1 = -1e30f, m2 = -1e30f;
      for (int j = 0; j < 4; ++j) {
        float v = scorr[g * 4 + j];
        if (v > m1) { m2 = m1; m1 = v; } else if (v > m2) m2 = v;
      }
      gs[g] = m1 + m2;
    }
    int g1 = 0;
    for (int g = 1; g < 4; ++g) if (gs[g] > gs[g1]) g1 = g;
    int g2 = -1;
    for (int g = 0; g < 4; ++g) { if (g == g1) continue; if (g2 < 0 || gs[g] > gs[g2]) g2 = g; }

    bool taken[NEXP];
    for (int e = 0; e < NEXP; ++e) taken[e] = false;
    int ids[TOPK]; float wv[TOPK]; float wsum = 0.f;
    for (int k = 0; k < TOPK; ++k) {
      int best = -1; float bv = -1e30f;
      for (int e = 0; e < NEXP; ++e) {
        int grp = e >> 2;
        if (grp != g1 && grp != g2) continue;
        if (taken[e]) continue;
        if (scorr[e] > bv) { bv = scorr[e]; best = e; }
      }
      taken[best] = true; ids[k] = best; wv[k] = sc[best]; wsum += sc[best];
    }
    float inv = 2.5f / wsum;
    for (int k = 0; k < TOPK; ++k) {
      int e = ids[k];
      int slot = atomicAdd(&counts[e], 1);
      tok_list[e * CAP + slot] = t;
      meta[t * TOPK + k] = (e << 16) | slot;
      pwt[t * TOPK + k] = wv[k] * inv;
    }
  }
}

// ------ 128x128 grouped GEMM, f32 B in-staging, depth-2 counted-vmcnt pipe --
// 4 waves (2x2), BK=64, dbuf LDS 64 KiB (2 blk/CU).
// Per tile t: issue gllA(t+1)+loadB(t+2) | compute(t) | WRITEB B(t+1)
// (compiler-counted vmcnt, issued a full tile ago) | vmcnt(8) drains A-glls |
// lgkmcnt(0) | raw s_barrier.  B(t+2)'s 8 loads STAY IN FLIGHT across the
// barrier (T4). Prefetch indices clamped at last tile => uniform vmcnt ledger.
// B swizzle: slot ^ ((r>>2)&7) ^ ((r&3)<<1) (write-free, read 2-way).
template<int MODE>
__global__ __launch_bounds__(256, 2) void gemm_fw_k(
    const unsigned short* __restrict__ A, int lda, size_t a_estride,
    const float* __restrict__ Wr, const float* __restrict__ Ws, int K,
    const int* __restrict__ counts, const int* __restrict__ tok_list,
    unsigned short* __restrict__ outb, int out_ld, size_t out_estride)
{
  int bx = blockIdx.x, by = blockIdx.y, bz = blockIdx.z;
  xcd_remap(bx, by, bz);
  const int e  = bz;
  const int m0 = by * 128;
  const int M  = (e < 16) ? counts[e] : N_TOK;
  if (m0 >= M) return;
  const int n0 = bx * (MODE == 0 ? 64 : 128);

  __shared__ __align__(16) unsigned short Al[2][128 * 64];   // 2 x 16 KB
  __shared__ __align__(16) unsigned short Bl[2][128 * 64];   // 2 x 16 KB

  const int tid = threadIdx.x, lane = tid & 63, wid = tid >> 6;
  const int wm = wid >> 1, wn = wid & 1, l15 = lane & 15, hi = lane >> 4;

  const unsigned short* Ap = A + (size_t)e * a_estride;

  // ---- A staging descriptors (gll16 w=16, inverse-swizzled source) ----
  const unsigned short* asrc[4]; int aoff[4];
  #pragma unroll
  for (int i = 0; i < 4; ++i) {
    int c = tid + 256 * i;                 // 0..1023, 16B each
    int r = c >> 3, s = c & 7, sl = s ^ (r & 7);
    int slot = m0 + r;
    int row;
    if (MODE == 0) row = (e < 16) ? ((slot < M) ? tok_list[e * CAP + slot] : 0) : slot;
    else           row = slot;
    asrc[i] = Ap + (size_t)row * lda + sl * 8;
    aoff[i] = c * 16;
  }

  // ---- B staging: thread owns n-rows nq*4..+3, k-range kb8*8..+7 ----
  const int nq = tid & 31, kb8 = tid >> 5;
  const float* bp; int ldw;
  {
    int n_ = nq * 4;
    if (MODE == 0) {
      if (e < 16) {
        size_t col = (n_ < 64) ? (size_t)(n0 + n_) : (size_t)(1024 + n0 + n_ - 64);
        bp = Wr + (size_t)e * HID * (2 * INTER) + col; ldw = 2 * INTER;
      } else {
        int j = e - 16;
        size_t col = (n_ < 64) ? (size_t)(j * 1024 + n0 + n_)
                               : (size_t)(2048 + j * 1024 + n0 + n_ - 64);
        bp = Ws + col; ldw = 4096;
      }
    } else {
      bp = ((e < 16) ? Wr + (size_t)e * INTER * HID
                     : Ws + (size_t)(e - 16) * INTER * HID) + (n0 + n_);
      ldw = HID;
    }
    bp += (size_t)(kb8 * 8) * ldw;
  }
  int bwoff[4];
  #pragma unroll
  for (int j = 0; j < 4; ++j)
    bwoff[j] = (nq * 4 + j) * 128 + ((kb8 ^ (nq & 7) ^ (j << 1)) << 4);

  int bn[4];
  if (MODE == 0) { bn[0] = wn*32; bn[1] = wn*32+16; bn[2] = 64+wn*32; bn[3] = 80+wn*32; }
  else           { bn[0] = wn*64; bn[1] = wn*64+16; bn[2] = wn*64+32; bn[3] = wn*64+48; }

  f32x4 acc[4][4];
  #pragma unroll
  for (int a0 = 0; a0 < 4; ++a0)
    #pragma unroll
    for (int b0 = 0; b0 < 4; ++b0) acc[a0][b0] = (f32x4){0.f, 0.f, 0.f, 0.f};

  float4 rb0[8], rb1[8];

  #define LOADB(rb, kt)                                                     \
    _Pragma("unroll")                                                       \
    for (int i = 0; i < 8; ++i)                                             \
      rb[i] = *(const float4*)(bp + (size_t)((kt) + i) * ldw);
  #define WRITEB(rb, Bb)                                                    \
    _Pragma("unroll")                                                       \
    for (int j = 0; j < 4; ++j) {                                           \
      unsigned w4[4];                                                       \
      _Pragma("unroll")                                                     \
      for (int q2 = 0; q2 < 4; ++q2) {                                      \
        float lo  = ((const float*)(rb + 2 * q2))[j];                       \
        float hi2 = ((const float*)(rb + 2 * q2 + 1))[j];                   \
        unsigned rr;                                                        \
        asm("v_cvt_pk_bf16_f32 %0, %1, %2" : "=v"(rr) : "v"(lo), "v"(hi2)); \
        w4[q2] = rr;                                                        \
      }                                                                     \
      *(uint4*)((char*)(Bb) + bwoff[j]) = *(uint4*)w4;                      \
    }
  #define COMPUTE(Ab, Bb)                                                   \
    _Pragma("unroll")                                                       \
    for (int kk = 0; kk < 64; kk += 32) {                                   \
      bf16x8 af[4], bv[4];                                                  \
      _Pragma("unroll")                                                     \
      for (int mi = 0; mi < 4; ++mi) {                                      \
        int r = wm * 64 + mi * 16 + l15;                                    \
        int off = (r * 128 + (kk + hi * 8) * 2) ^ ((r & 7) << 4);           \
        af[mi] = *(const bf16x8*)((const char*)(Ab) + off);                 \
      }                                                                     \
      _Pragma("unroll")                                                     \
      for (int ni = 0; ni < 4; ++ni) {                                      \
        int r = bn[ni] + l15;                                               \
        int slot = (kk >> 3) + hi;                                          \
        int off = r * 128 + ((slot ^ ((r >> 2) & 7) ^ ((r & 3) << 1)) << 4);\
        bv[ni] = *(const bf16x8*)((const char*)(Bb) + off);                 \
      }                                                                     \
      _Pragma("unroll")                                                     \
      for (int mi = 0; mi < 4; ++mi)                                        \
        _Pragma("unroll")                                                   \
        for (int ni = 0; ni < 4; ++ni)                                      \
          acc[mi][ni] = __builtin_amdgcn_mfma_f32_16x16x32_bf16(            \
              af[mi], bv[ni], acc[mi][ni], 0, 0, 0);                        \
    }

  const int nt = K >> 6;           // 32 or 16 (even)
  const int LT = (nt - 1) << 6;    // clamp for tail prefetch (L2-hot re-read)

  // ---- prologue: stage tile 0; leave B(1) in flight counts uniform ----
  LOADB(rb0, 0)                                   // B(0): 8 vmem
  #pragma unroll
  for (int i = 0; i < 4; ++i) gll16(asrc[i], (char*)Al[0] + aoff[i]);  // A(0): 4
  WRITEB(rb0, Bl[0])                              // compiler waits B(0)
  LOADB(rb0, 64 < K ? 64 : LT)                    // B(1): 8  (rb0 reused)
  asm volatile("s_waitcnt vmcnt(8)" ::: "memory");  // drain A(0); B(1) in flight
  asm volatile("s_waitcnt lgkmcnt(0)" ::: "memory");
  __builtin_amdgcn_s_barrier();
  __builtin_amdgcn_sched_barrier(0);

  for (int t = 0; t < nt; t += 2) {
    // ---- even tile t: buffers [0]; rb0 = B(t+1); rb1 <- B(t+2) ----
    {
      int ka = (t + 1 < nt) ? (t + 1) << 6 : LT;
      int kb = (t + 2 < nt) ? (t + 2) << 6 : LT;
      #pragma unroll
      for (int i = 0; i < 4; ++i) gll16(asrc[i] + ka, (char*)Al[1] + aoff[i]);
      LOADB(rb1, kb)
      __builtin_amdgcn_sched_barrier(0);
      COMPUTE(Al[0], Bl[0])
      WRITEB(rb0, Bl[1])                          // compiler-counted wait (vmcnt 12)
      __builtin_amdgcn_sched_barrier(0);
      asm volatile("s_waitcnt vmcnt(8)" ::: "memory");   // A(t+1) landed
      asm volatile("s_waitcnt lgkmcnt(0)" ::: "memory");
      __builtin_amdgcn_s_barrier();
      __builtin_amdgcn_sched_barrier(0);
    }
    // ---- odd tile t+1: buffers [1]; rb1 = B(t+2); rb0 <- B(t+3) ----
    {
      int ka = (t + 2 < nt) ? (t + 2) << 6 : LT;
      int kb = (t + 3 < nt) ? (t + 3) << 6 : LT;
      #pragma unroll
      for (int i = 0; i < 4; ++i) gll16(asrc[i] + ka, (char*)Al[0] + aoff[i]);
      LOADB(rb0, kb)
      __builtin_amdgcn_sched_barrier(0);
      COMPUTE(Al[1], Bl[1])
      WRITEB(rb1, Bl[0])
      __builtin_amdgcn_sched_barrier(0);
      asm volatile("s_waitcnt vmcnt(8)" ::: "memory");
      asm volatile("s_waitcnt lgkmcnt(0)" ::: "memory");
      __builtin_amdgcn_s_barrier();
      __builtin_amdgcn_sched_barrier(0);
    }
  }
  #undef LOADB
  #undef WRITEB
  #undef COMPUTE

  // ---- epilogue ----  C/D: col=lane&15, row=(lane>>4)*4+reg
  const int rbase = hi * 4;
  if (MODE == 0) {
    #pragma unroll
    for (int mi = 0; mi < 4; ++mi)
      #pragma unroll
      for (int rr = 0; rr < 4; ++rr) {
        int slot = m0 + wm * 64 + mi * 16 + rbase + rr;
        if (slot >= M) continue;
        #pragma unroll
        for (int j = 0; j < 2; ++j) {
          float g = acc[mi][j][rr], u = acc[mi][j + 2][rr];
          float sv = g / (1.f + expf(-g)) * u;
          int col = n0 + wn * 32 + j * 16 + l15;
          outb[(size_t)e * out_estride + (size_t)slot * out_ld + col] = f2bf(sv);
        }
      }
  } else {
    #pragma unroll
    for (int mi = 0; mi < 4; ++mi)
      #pragma unroll
      for (int rr = 0; rr < 4; ++rr) {
        int slot = m0 + wm * 64 + mi * 16 + rbase + rr;
        if (slot >= M) continue;
        unsigned short* row = outb + (size_t)e * out_estride + (size_t)slot * out_ld;
        #pragma unroll
        for (int ni = 0; ni < 4; ++ni)
          row[n0 + bn[ni] + l15] = f2bf(acc[mi][ni][rr]);
      }
  }
}

// ---------------------------------------------------------------- combine ---
__global__ __launch_bounds__(256) void combine_k(
    const unsigned short* __restrict__ ybuf, const int* __restrict__ meta,
    const float* __restrict__ pwt, float* __restrict__ out)
{
  const int t = blockIdx.x;
  const int c0 = threadIdx.x * 8;
  float acc[8];
  {
    bf16x8 v0 = *(const bf16x8*)(ybuf + ((size_t)16 * CAP + t) * HID + c0);
    bf16x8 v1 = *(const bf16x8*)(ybuf + ((size_t)17 * CAP + t) * HID + c0);
    #pragma unroll
    for (int j = 0; j < 8; ++j) acc[j] = b2f(v0[j]) + b2f(v1[j]);
  }
  #pragma unroll
  for (int k = 0; k < TOPK; ++k) {
    int m = meta[t * TOPK + k];
    float w = pwt[t * TOPK + k];
    int e = m >> 16, s = m & 0xffff;
    bf16x8 v = *(const bf16x8*)(ybuf + ((size_t)e * CAP + s) * HID + c0);
    #pragma unroll
    for (int j = 0; j < 8; ++j) acc[j] += w * b2f(v[j]);
  }
  float4* o = (float4*)(out + (size_t)t * HID + c0);
  o[0] = make_float4(acc[0], acc[1], acc[2], acc[3]);
  o[1] = make_float4(acc[4], acc[5], acc[6], acc[7]);
}

// --------------------------------------------------------------- launcher ---
extern "C" void kernel_launch(void* const* d_in, const int* in_sizes, int n_in,
                              void* d_out, int out_size, void* d_ws, size_t ws_size,
                              hipStream_t stream) {
  const float* x   = (const float*)d_in[0];
  const float* gw  = (const float*)d_in[1];
  const float* gb  = (const float*)d_in[2];
  const float* wgu = (const float*)d_in[3];
  const float* wd  = (const float*)d_in[4];
  const float* sgu = (const float*)d_in[5];
  const float* sd  = (const float*)d_in[6];
  float* out = (float*)d_out;

  char* ws = (char*)d_ws;
  int*   counts   = (int*)ws;                              // 256 B
  int*   tok_list = (int*)(ws + 256);                      // 64 KB
  int*   meta     = (int*)(ws + 256 + 65536);              // 24 KB
  float* pwt      = (float*)(ws + 256 + 65536 + 24576);    // 24 KB
  unsigned short* x_bf = (unsigned short*)(ws + 128 * 1024);          // 4 MiB
  unsigned short* act  = x_bf + (size_t)N_TOK * HID;                  // 36 MiB
  unsigned short* ybuf = act + (size_t)NE2 * CAP * INTER;             // 72 MiB
  const size_t need = (size_t)((char*)(ybuf + (size_t)NE2 * CAP * HID) - ws);
  if (ws_size < need) return;   // ws measured at 1 GiB; need ~112 MiB

  hipMemsetAsync(counts, 0, 256, stream);
  router_k<<<N_TOK, 256, 0, stream>>>(x, gw, gb, counts, tok_list, meta, pwt, x_bf);

  // gemm1: [18] gather(x)[M,2048] @ (wgu|sgu f32, converted in-staging)
  //        -> swiglu -> act[e][M,1024]
  gemm_fw_k<0><<<dim3(INTER / 64, CAP / 128, NE2), 256, 0, stream>>>(
      x_bf, HID, 0, wgu, sgu, HID, counts, tok_list,
      act, INTER, (size_t)CAP * INTER);
  // gemm2: [18] act[e][M,1024] @ (wd|sd f32, converted in-staging)
  //        -> ybuf[e][M,2048] (bf16)
  gemm_fw_k<1><<<dim3(HID / 128, CAP / 128, NE2), 256, 0, stream>>>(
      act, INTER, (size_t)CAP * INTER, wd, sd, INTER, counts, nullptr,
      ybuf, HID, (size_t)CAP * HID);

  combine_k<<<N_TOK, 256, 0, stream>>>(ybuf, meta, pwt, out);
}